// Round 1
// baseline (95.115 us; speedup 1.0000x reference)
//
#include <hip/hip_runtime.h>

// 3-level inverse Haar DWT, fully fused.
// Input  h  : (16, 192, 64, 64) f32
// Output out: (16, 3, 512, 512) f32
//
// Each thread produces a 2x4 output patch (rows 2*i0, 2*i0+1; cols 4*jq..4*jq+3),
// i.e. two adjacent level-0 2x2 synthesis blocks. It gathers:
//   1  LL  coefficient        (ch c,        spatial (i2,j2))
//   3  yh2 coefficients       (ch 183+3c+b, spatial (i2,j2))
//   3  yh1 coefficients       (ch 147+12c+4b+2*ph1+pw1)
//   3  yh0 float2 coefficients(ch 3+48c+16b+4*ph0+pw0)
// and combines with +-0.5 factors per level.

__global__ __launch_bounds__(256) void wave_decoder_kernel(
    const float* __restrict__ h, float* __restrict__ out) {
    const int tid = threadIdx.x;
    const int sp  = blockIdx.x * 256 + tid;   // [0, 32768) per (n,c) image
    const int jq  = sp & 127;                 // quad-column index [0,128)
    const int i0  = sp >> 7;                  // level-0 row index [0,256)
    const int nc  = blockIdx.y;               // n*3 + c, [0,48)
    const int c   = nc % 3;
    const float* __restrict__ hb = h + (size_t)(nc / 3) * (192 * 4096);

    const int i1 = i0 >> 1;                   // [0,128)
    const int j1 = jq;                        // [0,128)
    const int i2 = i1 >> 1;                   // [0,64)
    const int j2 = jq >> 1;                   // [0,64)

    // ---- level 2 (p=1, ch base 183) + LL (ch 0..2) ----
    const int s2 = i2 * 64 + j2;
    const float llv = hb[c * 4096 + s2];
    const float* __restrict__ y2 = hb + (183 + c * 3) * 4096 + s2;
    const float lh2 = y2[0];
    const float hl2 = y2[4096];
    const float hh2 = y2[2 * 4096];
    const float sx2 = (i1 & 1) ? -1.f : 1.f;
    const float sy2 = (j1 & 1) ? -1.f : 1.f;
    const float ll2v = 0.5f * ((llv + sx2 * lh2) + sy2 * (hl2 + sx2 * hh2));

    // ---- level 1 (p=2, ch base 147): ch = 147 + 12c + 4b + 2*ph + pw ----
    const int s1 = (i1 & 63) * 64 + (j1 & 63);
    const float* __restrict__ y1 =
        hb + (147 + c * 12 + (i1 >> 6) * 2 + (j1 >> 6)) * 4096 + s1;
    const float lh1 = y1[0];
    const float hl1 = y1[4 * 4096];
    const float hh1 = y1[8 * 4096];
    const float sx1 = (i0 & 1) ? -1.f : 1.f;
    const float t1 = ll2v + sx1 * lh1;
    const float u1 = hl1 + sx1 * hh1;
    const float ll1a = 0.5f * (t1 + u1);  // for even j0
    const float ll1b = 0.5f * (t1 - u1);  // for odd  j0

    // ---- level 0 (p=4, ch base 3): ch = 3 + 48c + 16b + 4*ph + pw ----
    const int j0 = jq << 1;               // even, [0,256)
    const int s0 = (i0 & 63) * 64 + (j0 & 63);   // even -> float2 aligned
    const float* __restrict__ y0 =
        hb + (3 + c * 48 + (i0 >> 6) * 4 + (j0 >> 6)) * 4096 + s0;
    const float2 lh0 = *(const float2*)(y0);
    const float2 hl0 = *(const float2*)(y0 + 16 * 4096);
    const float2 hh0 = *(const float2*)(y0 + 32 * 4096);

    float4 r0, r1;
    {   // columns 4jq, 4jq+1  (j0 even -> ll1a)
        float p = ll1a + lh0.x, q = hl0.x + hh0.x;
        r0.x = 0.5f * (p + q);  r0.y = 0.5f * (p - q);
        p = ll1a - lh0.x;       q = hl0.x - hh0.x;
        r1.x = 0.5f * (p + q);  r1.y = 0.5f * (p - q);
    }
    {   // columns 4jq+2, 4jq+3 (j0 odd -> ll1b)
        float p = ll1b + lh0.y, q = hl0.y + hh0.y;
        r0.z = 0.5f * (p + q);  r0.w = 0.5f * (p - q);
        p = ll1b - lh0.y;       q = hl0.y - hh0.y;
        r1.z = 0.5f * (p + q);  r1.w = 0.5f * (p - q);
    }

    float* __restrict__ ob = out + ((size_t)nc * 512 + (i0 << 1)) * 512 + (jq << 2);
    *(float4*)(ob)       = r0;   // row 2*i0
    *(float4*)(ob + 512) = r1;   // row 2*i0+1
}

extern "C" void kernel_launch(void* const* d_in, const int* in_sizes, int n_in,
                              void* d_out, int out_size, void* d_ws, size_t ws_size,
                              hipStream_t stream) {
    const float* h = (const float*)d_in[0];
    float* out = (float*)d_out;
    dim3 grid(128, 48);      // 128 spatial blocks x (n*3+c)
    wave_decoder_kernel<<<grid, dim3(256, 1, 1), 0, stream>>>(h, out);
}